// Round 18
// baseline (941.902 us; speedup 1.0000x reference)
//
#include <hip/hip_runtime.h>
#include <math.h>

#define FD 64
#define NRBF 20
#define CUT 5.0f
#define EPSV 1e-8f
#define PI_F 3.14159265358979f

typedef _Float16 h2v __attribute__((ext_vector_type(2)));

__device__ __forceinline__ float wredsum(float v){
#pragma unroll
  for (int m = 32; m >= 1; m >>= 1) v += __shfl_xor(v, m, 64);
  return v;
}
__device__ __forceinline__ float wredmax(float v){
#pragma unroll
  for (int m = 32; m >= 1; m >>= 1) v = fmaxf(v, __shfl_xor(v, m, 64));
  return v;
}
__device__ __forceinline__ float silu_f(float x){ return x * (1.0f / (1.0f + __expf(-x))); }
__device__ __forceinline__ h2v as_h2(unsigned u){
  union { unsigned u; h2v h; } x; x.u = u; return x.h;
}
__device__ __forceinline__ unsigned pack_bf16(float a, float b){
  unsigned ua = __float_as_uint(a), ub = __float_as_uint(b);
  ua = (ua + 0x7fffu + ((ua >> 16) & 1u)) >> 16;
  ub = (ub + 0x7fffu + ((ub >> 16) & 1u)) >> 16;
  return ua | (ub << 16);
}
__device__ __forceinline__ unsigned pack_f16(float a, float b){
  return __builtin_bit_cast(unsigned, __builtin_amdgcn_cvt_pkrtz(a, b));
}
#define BF_LO(u) __uint_as_float((u) << 16)
#define BF_HI(u) __uint_as_float((u) & 0xffff0000u)

// ---- CSR build: histogram, scan, scatter ----
__global__ __launch_bounds__(256) void k_count(const int* __restrict__ idx_i,
                                               int* __restrict__ cnt, int P)
{
  int p = blockIdx.x * blockDim.x + threadIdx.x;
  if (p < P) atomicAdd(&cnt[idx_i[p]], 1);
}

__global__ __launch_bounds__(1024) void k_scan(const int* __restrict__ cnt,
                                               int* __restrict__ start,
                                               int* __restrict__ cursor, int N)
{
  __shared__ int part[1024];
  int t = threadIdx.x;
  int chunk = (N + 1023) / 1024;
  int lo = t * chunk, hi = lo + chunk; if (hi > N) hi = N;
  int s = 0;
  for (int i = lo; i < hi; ++i) s += cnt[i];
  part[t] = s;
  __syncthreads();
  for (int off = 1; off < 1024; off <<= 1){
    int v = 0;
    if (t >= off) v = part[t - off];
    __syncthreads();
    if (t >= off) part[t] += v;
    __syncthreads();
  }
  int run = (t == 0) ? 0 : part[t-1];
  for (int i = lo; i < hi; ++i){ start[i] = run; cursor[i] = run; run += cnt[i]; }
  if (t == 1023) start[N] = run;
}

__global__ __launch_bounds__(256) void k_scatter(const int* __restrict__ idx_i,
                                                 int* __restrict__ cursor,
                                                 int* __restrict__ elist, int P)
{
  int p = blockIdx.x * blockDim.x + threadIdx.x;
  if (p < P){
    int pos = atomicAdd(&cursor[idx_i[p]], 1);
    elist[pos] = p;
  }
}

// ---- edge records in CSR order, 64B each ----
__global__ __launch_bounds__(256) void k_edgeprep(const float* __restrict__ Rij,
                                                  const int* __restrict__ elist,
                                                  const int* __restrict__ idx_j,
                                                  float* __restrict__ eP,
                                                  int* __restrict__ eJ, int P)
{
  int e = blockIdx.x * blockDim.x + threadIdx.x;
  if (e >= P) return;
  int p = elist[e];
  eJ[e] = idx_j[p];
  float rx = Rij[3*p+0], ry = Rij[3*p+1], rz = Rij[3*p+2];
  float d = sqrtf(rx*rx + ry*ry + rz*rz);
  float inv = 1.0f / d;
  float fc = (d < CUT) ? 0.5f * (__cosf(PI_F * d / CUT) + 1.0f) : 0.0f;
  float* pr = eP + (size_t)e * 16;
  pr[0] = rx*inv; pr[1] = ry*inv; pr[2] = rz*inv; pr[3] = fc;
  const float width = CUT / (float)(NRBF - 1);
  float ph[NRBF];
#pragma unroll
  for (int r = 0; r < NRBF; ++r){
    float t = (d - width * (float)r) / width;
    ph[r] = __expf(-0.5f * t * t) * fc;
  }
  unsigned* pu = (unsigned*)(pr + 4);
#pragma unroll
  for (int r = 0; r < 10; ++r) pu[r] = pack_f16(ph[2*r], ph[2*r+1]);
  pr[14] = 0.f; pr[15] = 0.f;
}

// ---- transpose rec_W2 -> f16 rW2S in [l][c][kq][f][8] layout; rb2 -> rb2T ----
__global__ __launch_bounds__(256) void k_transpose_w(const float* __restrict__ rW2,
                                                     const float* __restrict__ rb2,
                                                     unsigned short* __restrict__ rW2S,
                                                     float* __restrict__ rb2T)
{
  int t = blockIdx.x * blockDim.x + threadIdx.x;
  if (t < 2*64*64*32){
    int km = t & 7;
    int f  = (t >> 3) & 63;
    int kq = (t >> 9) & 3;
    int c  = (t >> 11) & 63;
    int l  = t >> 17;
    int k  = kq*8 + km;
    float v = rW2[((size_t)(l*32 + k))*4096 + f*64 + c];
    _Float16 hv = (_Float16)v;
    unsigned short us;
    __builtin_memcpy(&us, &hv, 2);
    rW2S[t] = us;
  }
  if (t < 2*64*64){
    int f = t & 63, c = (t >> 6) & 63, l = t >> 12;
    rb2T[t] = rb2[(size_t)l*4096 + f*64 + c];
  }
}

// ---- K_init: q = embed[Z] ----
__global__ __launch_bounds__(256) void k_init_q(const int* __restrict__ Z,
                                                const float* __restrict__ embed,
                                                float* __restrict__ q, int Ntot)
{
  int t = blockIdx.x * blockDim.x + threadIdx.x;
  if (t >= Ntot * FD) return;
  int n = t >> 6, f = t & 63;
  q[t] = embed[Z[n]*FD + f];
}

// ---- K1: per-atom pre. 16 atoms/block, weights LDS-staged. ----
__global__ __launch_bounds__(256) void k_atom_pre(
    const float* __restrict__ q, const float* __restrict__ mu,
    const float* __restrict__ cW1, const float* __restrict__ cb1,
    const float* __restrict__ cW2, const float* __restrict__ cb2,
    const float* __restrict__ pW1, const float* __restrict__ pb1,
    const float* __restrict__ pW2, const float* __restrict__ pb2,
    unsigned* __restrict__ XCVh, float* __restrict__ CVf, int Ntot)
{
  __shared__ float wbuf[12288];     // 48 KB
  __shared__ float qs[16][64];      // 4 KB
  __shared__ float sbuf[16][128];   // 8 KB
  __shared__ float h1s[16][64];     // 4 KB
  __shared__ float hcs[16][32];     // 2 KB
  int t = threadIdx.x;
  int w = t >> 6, f = t & 63;
  int base = blockIdx.x * 16;
  const int aw = w * 4;
  float4* wt4 = (float4*)wbuf;

  float m0a[4], m1a[4], m2a[4], m0b[4], m1b[4], m2b[4];
#pragma unroll
  for (int s = 0; s < 4; ++s){
    int a = aw + s;
    int n = base + a; if (n >= Ntot) n = Ntot - 1;
    qs[a][f] = q[(size_t)n*64 + f];
    const float* mun = mu + (size_t)n * 384;
    m0a[s] = mun[0*128 + f];      m1a[s] = mun[1*128 + f];      m2a[s] = mun[2*128 + f];
    m0b[s] = mun[0*128 + 64 + f]; m1b[s] = mun[1*128 + 64 + f]; m2b[s] = mun[2*128 + 64 + f];
    sbuf[a][f]      = sqrtf(m0a[s]*m0a[s] + m1a[s]*m1a[s] + m2a[s]*m2a[s] + EPSV);
    sbuf[a][64 + f] = sqrtf(m0b[s]*m0b[s] + m1b[s]*m1b[s] + m2b[s]*m2b[s] + EPSV);
  }
#pragma unroll
  for (int i = 0; i < 4; ++i) wt4[t + i*256] = ((const float4*)cW1)[t + i*256];
  __syncthreads();

  float hacc[4];
#pragma unroll
  for (int s = 0; s < 4; ++s) hacc[s] = cb1[f];
  for (int k = 0; k < 64; ++k){
    float wv = wbuf[k*64 + f];
#pragma unroll
    for (int s = 0; s < 4; ++s) hacc[s] = fmaf(qs[aw + s][k], wv, hacc[s]);
  }
#pragma unroll
  for (int s = 0; s < 4; ++s) h1s[aw + s][f] = silu_f(hacc[s]);

  __syncthreads();
#pragma unroll
  for (int i = 0; i < 12; ++i) wt4[t + i*256] = ((const float4*)cW2)[t + i*256];
  __syncthreads();

  float x0[4], x1[4], x2[4];
#pragma unroll
  for (int s = 0; s < 4; ++s){ x0[s] = cb2[f]; x1[s] = cb2[64+f]; x2[s] = cb2[128+f]; }
  for (int k = 0; k < 64; ++k){
    float u0 = wbuf[k*192 + f];
    float u1 = wbuf[k*192 + 64 + f];
    float u2 = wbuf[k*192 + 128 + f];
#pragma unroll
    for (int s = 0; s < 4; ++s){
      float h = h1s[aw + s][k];
      x0[s] = fmaf(h, u0, x0[s]); x1[s] = fmaf(h, u1, x1[s]); x2[s] = fmaf(h, u2, x2[s]);
    }
  }
#pragma unroll
  for (int s = 0; s < 4; ++s){
    int n = base + aw + s;
    if (n < Ntot) XCVh[(size_t)n*192 + f] = pack_bf16(x0[s], x1[s]);
  }

  __syncthreads();
#pragma unroll
  for (int i = 0; i < 4; ++i) wt4[t + i*256] = ((const float4*)pW1)[t + i*256];
#pragma unroll
  for (int i = 0; i < 2; ++i) wt4[1024 + t + i*256] = ((const float4*)pW2)[t + i*256];
  __syncthreads();

  int ki = f & 31;
#pragma unroll
  for (int p = 0; p < 2; ++p){
    int a_h = aw + p*2 + (f >> 5);
    float ah = pb1[ki];
#pragma unroll 4
    for (int c = 0; c < 128; ++c) ah = fmaf(sbuf[a_h][c], wbuf[c*32 + ki], ah);
    hcs[a_h][ki] = fmaxf(ah, 0.0f);
  }

  float logit[4];
#pragma unroll
  for (int s = 0; s < 4; ++s) logit[s] = pb2[f];
  for (int k = 0; k < 32; ++k){
    float wv = wbuf[4096 + k*64 + f];
#pragma unroll
    for (int s = 0; s < 4; ++s) logit[s] = fmaf(hcs[aw + s][k], wv, logit[s]);
  }
#pragma unroll
  for (int s = 0; s < 4; ++s){
    float mx = wredmax(logit[s]);
    float e  = __expf(logit[s] - mx);
    float se = wredsum(e);
    float wt = e / se;
    float v0 = wredsum(m0a[s] + m0b[s]);
    float v1 = wredsum(m1a[s] + m1b[s]);
    float v2 = wredsum(m2a[s] + m2b[s]);
    int n = base + aw + s;
    if (n < Ntot){
      float cv0 = v0 * wt, cv1 = v1 * wt, cv2 = v2 * wt;
      XCVh[(size_t)n*192 + 64 + f]  = pack_bf16(x2[s], cv0);
      XCVh[(size_t)n*192 + 128 + f] = pack_bf16(cv1, cv2);
      float* cvn = CVf + (size_t)n*192;
      cvn[f] = cv0; cvn[64+f] = cv1; cvn[128+f] = cv2;
    }
  }
}

// ---- K2: gather, unroll-4 edge pipeline, fdot2 MLP, bf16 XCV. ----
__global__ __launch_bounds__(256) void k_gather(
    const float* __restrict__ eP, const int* __restrict__ eJ,
    const int* __restrict__ start,
    const float* __restrict__ fW, const float* __restrict__ fb,
    const unsigned* __restrict__ XCVh,
    float* __restrict__ dq, float* __restrict__ dmu, int l, int Ntot)
{
  int w = threadIdx.x >> 6;
  int f = threadIdx.x & 63;
  int i = blockIdx.x * 4 + w;
  if (i >= Ntot) return;
  const int col = l * 192;

  unsigned fwp0[10], fwp1[10], fwp2[10];
#pragma unroll
  for (int r = 0; r < 10; ++r){
    const float* fa = fW + (2*r)*384 + col;
    const float* fbp = fW + (2*r+1)*384 + col;
    fwp0[r] = pack_f16(fa[f],       fbp[f]);
    fwp1[r] = pack_f16(fa[64 + f],  fbp[64 + f]);
    fwp2[r] = pack_f16(fa[128 + f], fbp[128 + f]);
  }
  float fb0 = fb[col + f], fb1 = fb[col + 64 + f], fb2 = fb[col + 128 + f];

  float dqa = 0.f, dm0 = 0.f, dm1 = 0.f, dm2 = 0.f;
  int e0 = start[i], e1 = start[i+1];
  int e = e0;
  for (; e + 4 <= e1; e += 4){
    int jj[4];
    float4 d4[4];
    uint4  p0[4], p1[4], p2[4];
    unsigned xv0[4], xv1[4], xv2[4];
#pragma unroll
    for (int u = 0; u < 4; ++u) jj[u] = eJ[e + u];
#pragma unroll
    for (int u = 0; u < 4; ++u){
      const float4* pr = (const float4*)(eP + (size_t)(e + u) * 16);
      const uint4*  pui = (const uint4*)pr;
      d4[u] = pr[0]; p0[u] = pui[1]; p1[u] = pui[2]; p2[u] = pui[3];
    }
#pragma unroll
    for (int u = 0; u < 4; ++u){
      const unsigned* xj = XCVh + (size_t)jj[u] * 192;
      xv0[u] = xj[f]; xv1[u] = xj[64 + f]; xv2[u] = xj[128 + f];
    }
#pragma unroll
    for (int u = 0; u < 4; ++u){
      unsigned ph[10] = {p0[u].x,p0[u].y,p0[u].z,p0[u].w,
                         p1[u].x,p1[u].y,p1[u].z,p1[u].w,
                         p2[u].x,p2[u].y};
      float fc = d4[u].w;
      float w0 = fb0 * fc, w1 = fb1 * fc, w2 = fb2 * fc;
#pragma unroll
      for (int r = 0; r < 10; ++r){
        w0 = __builtin_amdgcn_fdot2(as_h2(ph[r]), as_h2(fwp0[r]), w0, false);
        w1 = __builtin_amdgcn_fdot2(as_h2(ph[r]), as_h2(fwp1[r]), w1, false);
        w2 = __builtin_amdgcn_fdot2(as_h2(ph[r]), as_h2(fwp2[r]), w2, false);
      }
      dqa = fmaf(BF_LO(xv0[u]), w0, dqa);
      float dmR = BF_HI(xv0[u]) * w1, dmm = BF_LO(xv1[u]) * w2;
      dm0 = fmaf(dmR, d4[u].x, fmaf(dmm, BF_HI(xv1[u]), dm0));
      dm1 = fmaf(dmR, d4[u].y, fmaf(dmm, BF_LO(xv2[u]), dm1));
      dm2 = fmaf(dmR, d4[u].z, fmaf(dmm, BF_HI(xv2[u]), dm2));
    }
  }
  for (; e < e1; ++e){
    int j = eJ[e];
    const float4* pr = (const float4*)(eP + (size_t)e * 16);
    const uint4*  pu = (const uint4*)pr;
    float4 A0 = pr[0];
    uint4  Ap0 = pu[1], Ap1 = pu[2], Ap2 = pu[3];
    const unsigned* xj = XCVh + (size_t)j * 192;
    unsigned u0=xj[f], u1=xj[64+f], u2=xj[128+f];
    unsigned ph[10] = {Ap0.x,Ap0.y,Ap0.z,Ap0.w, Ap1.x,Ap1.y,Ap1.z,Ap1.w, Ap2.x,Ap2.y};
    float w0 = fb0 * A0.w, w1 = fb1 * A0.w, w2 = fb2 * A0.w;
#pragma unroll
    for (int r = 0; r < 10; ++r){
      w0 = __builtin_amdgcn_fdot2(as_h2(ph[r]), as_h2(fwp0[r]), w0, false);
      w1 = __builtin_amdgcn_fdot2(as_h2(ph[r]), as_h2(fwp1[r]), w1, false);
      w2 = __builtin_amdgcn_fdot2(as_h2(ph[r]), as_h2(fwp2[r]), w2, false);
    }
    dqa = fmaf(BF_LO(u0), w0, dqa);
    float dmR = BF_HI(u0) * w1, dmm = BF_LO(u1) * w2;
    dm0 = fmaf(dmR, A0.x, fmaf(dmm, BF_HI(u1), dm0));
    dm1 = fmaf(dmR, A0.y, fmaf(dmm, BF_LO(u2), dm1));
    dm2 = fmaf(dmR, A0.z, fmaf(dmm, BF_HI(u2), dm2));
  }
  dq[(size_t)i*64 + f] = dqa;
  float* dmn = dmu + (size_t)i*192;
  dmn[f] = dm0; dmn[64 + f] = dm1; dmn[128 + f] = dm2;
}

// ---- K3 fused: tv (phase A) + mixing (phase B). 16 atoms/block, 512 thr,
// 2 atoms/wave. LDS 52 KB -> 3 blocks/CU. mus reused as mua; svs/rbt region
// reused as ava; h2a overlays dead mus. mW2 staged in two 24 KB halves. ----
__global__ __launch_bounds__(512) void k_post(
    float* __restrict__ q, float* __restrict__ mu,
    const float* __restrict__ dq, const float* __restrict__ dmuA,
    const float* __restrict__ CVf,
    const float* __restrict__ rW1, const float* __restrict__ rb1,
    const unsigned short* __restrict__ rW2S, const float* __restrict__ rb2Tl,
    const float* __restrict__ mW1, const float* __restrict__ mb1,
    const float* __restrict__ mW2, const float* __restrict__ mb2,
    const float* __restrict__ Wm, int Ntot)
{
  __shared__ float mus[16][3][64];  // 12 KB (phase B: h2a overlays)
  __shared__ float svr[2048];       // 8 KB: A = svs[16][64](4K)+rbt[8][64](2K)+pad; B = ava[16][128]
  __shared__ float wbuf[8192];      // 32 KB tile buffer
  int t = threadIdx.x;
  int w = t >> 6, f = t & 63;
  int base = blockIdx.x * 16;
  float4* wt4 = (float4*)wbuf;
  float* svs = svr;              // [16][64]
  float* rbt = svr + 1024;       // [8][64]
  float* ava = svr;              // [16][128] (phase B)
  float* h2a = (float*)mus;      // [16][64]  (phase B)

  const int a0i = w*2, a1i = a0i + 1;

  // ---- A1: mu_int, s-norm, qn ----
  float qv0, qv1;
#pragma unroll
  for (int s = 0; s < 2; ++s){
    int a = a0i + s;
    int n = base + a; if (n >= Ntot) n = Ntot - 1;
    const float* dmn = dmuA + (size_t)n*192;
    const float* cvn = CVf  + (size_t)n*192;
    float m0 = dmn[f]       + cvn[f];
    float m1 = dmn[64 + f]  + cvn[64 + f];
    float m2 = dmn[128 + f] + cvn[128 + f];
    mus[a][0][f] = m0; mus[a][1][f] = m1; mus[a][2][f] = m2;
    svs[a*64 + f] = sqrtf(m0*m0 + m1*m1 + m2*m2 + EPSV);
    float qn = q[(size_t)n*64 + f] + dq[(size_t)n*64 + f];
    if (s == 0) qv0 = qn; else qv1 = qn;
  }
  __syncthreads();

  // ---- A2: rec-MLP hidden, pack f16 pairs ----
  int ki = f & 31;
  int a_h = a0i + (f >> 5);
  float ah = rb1[ki];
#pragma unroll
  for (int c = 0; c < 64; ++c) ah = fmaf(svs[a_h*64 + c], rW1[c*32 + ki], ah);
  ah = fmaxf(ah, 0.0f);
  unsigned hpk0[16], hpk1[16];
#pragma unroll
  for (int k = 0; k < 16; ++k){
    float a0 = __shfl(ah, 2*k, 64),      b0 = __shfl(ah, 2*k + 1, 64);
    float a1 = __shfl(ah, 32 + 2*k, 64), b1 = __shfl(ah, 32 + 2*k + 1, 64);
    hpk0[k] = pack_f16(a0, b0);
    hpk1[k] = pack_f16(a1, b1);
  }

  float mf00 = mus[a0i][0][f], mf01 = mus[a0i][1][f], mf02 = mus[a0i][2][f];
  float mf10 = mus[a1i][0][f], mf11 = mus[a1i][1][f], mf12 = mus[a1i][2][f];
  float tv00=0,tv01=0,tv02=0, tv10=0,tv11=0,tv12=0;
  const uint4* wtu = reinterpret_cast<const uint4*>(wt4);

  // ---- A3: fused sw/tv over 8 LDS tiles ----
  for (int ct = 0; ct < 8; ++ct){
    __syncthreads();
    const float4* src = (const float4*)rW2S + (size_t)ct*2048;
#pragma unroll
    for (int i = 0; i < 4; ++i) wt4[t + i*512] = src[t + i*512];
    if (t < 128) ((float4*)rbt)[t] = ((const float4*)(rb2Tl + ct*512))[t];
    __syncthreads();

#pragma unroll
    for (int cc = 0; cc < 8; ++cc){
      int c = ct*8 + cc;
      float u00 = mus[a0i][0][c], u01 = mus[a0i][1][c], u02 = mus[a0i][2][c];
      float u10 = mus[a1i][0][c], u11 = mus[a1i][1][c], u12 = mus[a1i][2][c];
      float g0 = u00*mf00 + u01*mf01 + u02*mf02;
      float g1 = u10*mf10 + u11*mf11 + u12*mf12;
      float a0A = rbt[cc*64 + f], a0B = 0.f;
      float a1A = a0A,            a1B = 0.f;
      uint4 uA = wtu[(cc*4 + 0)*64 + f];
      uint4 uB = wtu[(cc*4 + 2)*64 + f];
#pragma unroll
      for (int x = 0; x < 4; ++x){
        unsigned wA = (&uA.x)[x], wB = (&uB.x)[x];
        a0A = __builtin_amdgcn_fdot2(as_h2(wA), as_h2(hpk0[x]),     a0A, false);
        a0B = __builtin_amdgcn_fdot2(as_h2(wB), as_h2(hpk0[8 + x]), a0B, false);
        a1A = __builtin_amdgcn_fdot2(as_h2(wA), as_h2(hpk1[x]),     a1A, false);
        a1B = __builtin_amdgcn_fdot2(as_h2(wB), as_h2(hpk1[8 + x]), a1B, false);
      }
      uA = wtu[(cc*4 + 1)*64 + f];
      uB = wtu[(cc*4 + 3)*64 + f];
#pragma unroll
      for (int x = 0; x < 4; ++x){
        unsigned wA = (&uA.x)[x], wB = (&uB.x)[x];
        a0A = __builtin_amdgcn_fdot2(as_h2(wA), as_h2(hpk0[4 + x]),  a0A, false);
        a0B = __builtin_amdgcn_fdot2(as_h2(wB), as_h2(hpk0[12 + x]), a0B, false);
        a1A = __builtin_amdgcn_fdot2(as_h2(wA), as_h2(hpk1[4 + x]),  a1A, false);
        a1B = __builtin_amdgcn_fdot2(as_h2(wB), as_h2(hpk1[12 + x]), a1B, false);
      }
      float mm0 = (a0A + a0B) * g0, mm1 = (a1A + a1B) * g1;
      tv00 = fmaf(u00, mm0, tv00); tv01 = fmaf(u01, mm0, tv01); tv02 = fmaf(u02, mm0, tv02);
      tv10 = fmaf(u10, mm1, tv10); tv11 = fmaf(u11, mm1, tv11); tv12 = fmaf(u12, mm1, tv12);
    }
  }

  // ---- B1: stage Wm (32 KB), muV/muW per atom; ava = [qn | muVn] ----
  __syncthreads();   // all waves done with wt4/rbt
#pragma unroll
  for (int i = 0; i < 4; ++i) wt4[t + i*512] = ((const float4*)Wm)[t + i*512];
  __syncthreads();

  float V00=0,V01=0,V02=0, W00=0,W01=0,W02=0;
  float V10=0,V11=0,V12=0, W10=0,W11=0,W12=0;
  for (int k = 0; k < 64; ++k){
    float wv = wbuf[k*128 + f];
    float ww = wbuf[k*128 + 64 + f];
    float b00 = mus[a0i][0][k], b01 = mus[a0i][1][k], b02 = mus[a0i][2][k];
    float b10 = mus[a1i][0][k], b11 = mus[a1i][1][k], b12 = mus[a1i][2][k];
    V00 = fmaf(b00, wv, V00); V01 = fmaf(b01, wv, V01); V02 = fmaf(b02, wv, V02);
    W00 = fmaf(b00, ww, W00); W01 = fmaf(b01, ww, W01); W02 = fmaf(b02, ww, W02);
    V10 = fmaf(b10, wv, V10); V11 = fmaf(b11, wv, V11); V12 = fmaf(b12, wv, V12);
    W10 = fmaf(b10, ww, W10); W11 = fmaf(b11, ww, W11); W12 = fmaf(b12, ww, W12);
  }
  float dot0 = V00*W00 + V01*W01 + V02*W02;
  float dot1 = V10*W10 + V11*W11 + V12*W12;
  // ---- B2: stage mW1 (32 KB); h2 = silu(av @ mW1 + b1) ----
  __syncthreads();   // everyone done reading Wm from wbuf & mus in B1
  ava[a0i*128 + f] = qv0; ava[a0i*128 + 64 + f] = sqrtf(V00*V00 + V01*V01 + V02*V02 + EPSV);
  ava[a1i*128 + f] = qv1; ava[a1i*128 + 64 + f] = sqrtf(V10*V10 + V11*V11 + V12*V12 + EPSV);
#pragma unroll
  for (int i = 0; i < 4; ++i) wt4[t + i*512] = ((const float4*)mW1)[t + i*512];
  __syncthreads();

  float acc0 = mb1[f], acc1 = acc0;
  for (int k = 0; k < 128; ++k){
    float wv = wbuf[k*64 + f];
    acc0 = fmaf(ava[a0i*128 + k], wv, acc0);
    acc1 = fmaf(ava[a1i*128 + k], wv, acc1);
  }
  __syncthreads();   // mus reads done (B1); safe to overlay h2a
  h2a[a0i*64 + f] = silu_f(acc0);
  h2a[a1i*64 + f] = silu_f(acc1);

  // ---- B3: stage mW2 in two 24 KB halves; y accumulation ----
  float y00 = mb2[f], y01 = mb2[64+f], y02 = mb2[128+f];
  float y10 = y00, y11 = y01, y12 = y02;
  __syncthreads();
#pragma unroll
  for (int i = 0; i < 3; ++i) wt4[t + i*512] = ((const float4*)mW2)[t + i*512];
  __syncthreads();
  for (int k = 0; k < 32; ++k){
    float u0 = wbuf[k*192 + f];
    float u1 = wbuf[k*192 + 64 + f];
    float u2 = wbuf[k*192 + 128 + f];
    float h0 = h2a[a0i*64 + k], h1 = h2a[a1i*64 + k];
    y00 = fmaf(h0, u0, y00); y01 = fmaf(h0, u1, y01); y02 = fmaf(h0, u2, y02);
    y10 = fmaf(h1, u0, y10); y11 = fmaf(h1, u1, y11); y12 = fmaf(h1, u2, y12);
  }
  __syncthreads();
#pragma unroll
  for (int i = 0; i < 3; ++i) wt4[t + i*512] = ((const float4*)(mW2 + 6144))[t + i*512];
  __syncthreads();
  for (int k = 0; k < 32; ++k){
    float u0 = wbuf[k*192 + f];
    float u1 = wbuf[k*192 + 64 + f];
    float u2 = wbuf[k*192 + 128 + f];
    float h0 = h2a[a0i*64 + 32 + k], h1 = h2a[a1i*64 + 32 + k];
    y00 = fmaf(h0, u0, y00); y01 = fmaf(h0, u1, y01); y02 = fmaf(h0, u2, y02);
    y10 = fmaf(h1, u0, y10); y11 = fmaf(h1, u1, y11); y12 = fmaf(h1, u2, y12);
  }

  // ---- write-out ----
  int n0 = base + a0i, n1 = base + a1i;
  if (n0 < Ntot){
    q[(size_t)n0*64 + f] = qv0 + y00 + y02*dot0;
    float* mun = mu + (size_t)n0*384;
    mun[0*128 + f] = fmaf(y01, W00, mf00); mun[0*128 + 64 + f] = tv00;
    mun[1*128 + f] = fmaf(y01, W01, mf01); mun[1*128 + 64 + f] = tv01;
    mun[2*128 + f] = fmaf(y01, W02, mf02); mun[2*128 + 64 + f] = tv02;
  }
  if (n1 < Ntot){
    q[(size_t)n1*64 + f] = qv1 + y10 + y12*dot1;
    float* mun = mu + (size_t)n1*384;
    mun[0*128 + f] = fmaf(y11, W10, mf10); mun[0*128 + 64 + f] = tv10;
    mun[1*128 + f] = fmaf(y11, W11, mf11); mun[1*128 + 64 + f] = tv11;
    mun[2*128 + f] = fmaf(y11, W12, mf12); mun[2*128 + 64 + f] = tv12;
  }
}

extern "C" void kernel_launch(void* const* d_in, const int* in_sizes, int n_in,
                              void* d_out, int out_size, void* d_ws, size_t ws_size,
                              hipStream_t stream)
{
  const int*   Z      = (const int*)  d_in[0];
  const float* Rij    = (const float*)d_in[1];
  const int*   idx_i  = (const int*)  d_in[2];
  const int*   idx_j  = (const int*)  d_in[3];
  const float* embed  = (const float*)d_in[5];
  const float* fW     = (const float*)d_in[6];
  const float* fb     = (const float*)d_in[7];
  const float* ctxW1  = (const float*)d_in[8];
  const float* ctxb1  = (const float*)d_in[9];
  const float* ctxW2  = (const float*)d_in[10];
  const float* ctxb2  = (const float*)d_in[11];
  const float* compW1 = (const float*)d_in[12];
  const float* compb1 = (const float*)d_in[13];
  const float* compW2 = (const float*)d_in[14];
  const float* compb2 = (const float*)d_in[15];
  const float* recW1  = (const float*)d_in[16];
  const float* recb1  = (const float*)d_in[17];
  const float* recW2  = (const float*)d_in[18];
  const float* recb2  = (const float*)d_in[19];
  const float* mixW1  = (const float*)d_in[20];
  const float* mixb1  = (const float*)d_in[21];
  const float* mixW2  = (const float*)d_in[22];
  const float* mixb2  = (const float*)d_in[23];
  const float* muMixW = (const float*)d_in[24];

  const int N = in_sizes[0];
  const int P = in_sizes[1] / 3;

  float* ws    = (float*)d_ws;
  float* eP    = ws;                         // P*16 (64B records)
  float* q     = eP    + (size_t)P*16;       // N*64
  float* mu    = q     + (size_t)N*64;       // N*384
  float* XCVhf = mu    + (size_t)N*384;      // N*192 (uints)
  float* CVf   = XCVhf + (size_t)N*192;      // N*192
  float* dq    = CVf   + (size_t)N*192;      // N*64
  float* dmu   = dq    + (size_t)N*64;       // N*192
  float* rW2Sf = dmu   + (size_t)N*192;      // f16 512KB = 131072 floats
  float* rb2T  = rW2Sf + (size_t)131072;     // 8192
  int*   cnt    = (int*)(rb2T + (size_t)8192); // N
  int*   startA = cnt    + N;                  // N+1
  int*   cursor = startA + (N + 1);            // N
  int*   elist  = cursor + N;                  // P
  int*   eJ     = elist  + P;                  // P
  unsigned*       XCVh = (unsigned*)XCVhf;
  unsigned short* rW2S = (unsigned short*)rW2Sf;

  hipMemsetAsync(mu, 0, (size_t)N*384*sizeof(float), stream);
  hipMemsetAsync(cnt, 0, (size_t)N*sizeof(int), stream);
  k_init_q<<<(N*FD + 255)/256, 256, 0, stream>>>(Z, embed, q, N);
  k_transpose_w<<<(2*64*64*32 + 255)/256, 256, 0, stream>>>(recW2, recb2, rW2S, rb2T);

  // CSR build + CSR-ordered edge records (idx fixed across layers)
  k_count<<<(P + 255)/256, 256, 0, stream>>>(idx_i, cnt, P);
  k_scan<<<1, 1024, 0, stream>>>(cnt, startA, cursor, N);
  k_scatter<<<(P + 255)/256, 256, 0, stream>>>(idx_i, cursor, elist, P);
  k_edgeprep<<<(P + 255)/256, 256, 0, stream>>>(Rij, elist, idx_j, eP, eJ, P);

  const int ablk4  = (N + 3) / 4;
  const int ablk16 = (N + 15) / 16;
  for (int l = 0; l < 2; ++l){
    k_atom_pre<<<ablk16, 256, 0, stream>>>(q, mu,
        ctxW1 + (size_t)l*64*64,  ctxb1 + (size_t)l*64,
        ctxW2 + (size_t)l*64*192, ctxb2 + (size_t)l*192,
        compW1 + (size_t)l*128*32, compb1 + (size_t)l*32,
        compW2 + (size_t)l*32*64,  compb2 + (size_t)l*64,
        XCVh, CVf, N);
    k_gather<<<ablk4, 256, 0, stream>>>(eP, eJ, startA, fW, fb, XCVh,
        dq, dmu, l, N);
    k_post<<<ablk16, 512, 0, stream>>>(q, mu, dq, dmu, CVf,
        recW1 + (size_t)l*64*32, recb1 + (size_t)l*32,
        rW2S + (size_t)l*131072, rb2T + (size_t)l*4096,
        mixW1 + (size_t)l*128*64, mixb1 + (size_t)l*64,
        mixW2 + (size_t)l*64*192, mixb2 + (size_t)l*192,
        muMixW + (size_t)l*64*128, N);
  }

  hipMemcpyAsync(d_out, q, (size_t)N*64*sizeof(float), hipMemcpyDeviceToDevice, stream);
  hipMemcpyAsync((float*)d_out + (size_t)N*64, mu, (size_t)N*384*sizeof(float),
                 hipMemcpyDeviceToDevice, stream);
}

// Round 19
// 530.425 us; speedup vs baseline: 1.7757x; 1.7757x over previous
//
#include <hip/hip_runtime.h>
#include <math.h>

#define FD 64
#define NRBF 20
#define CUT 5.0f
#define EPSV 1e-8f
#define PI_F 3.14159265358979f

typedef _Float16 h2v __attribute__((ext_vector_type(2)));

__device__ __forceinline__ float wredsum(float v){
#pragma unroll
  for (int m = 32; m >= 1; m >>= 1) v += __shfl_xor(v, m, 64);
  return v;
}
__device__ __forceinline__ float wredmax(float v){
#pragma unroll
  for (int m = 32; m >= 1; m >>= 1) v = fmaxf(v, __shfl_xor(v, m, 64));
  return v;
}
__device__ __forceinline__ float silu_f(float x){ return x * (1.0f / (1.0f + __expf(-x))); }
__device__ __forceinline__ h2v as_h2(unsigned u){
  union { unsigned u; h2v h; } x; x.u = u; return x.h;
}
__device__ __forceinline__ unsigned pack_bf16(float a, float b){
  unsigned ua = __float_as_uint(a), ub = __float_as_uint(b);
  ua = (ua + 0x7fffu + ((ua >> 16) & 1u)) >> 16;
  ub = (ub + 0x7fffu + ((ub >> 16) & 1u)) >> 16;
  return ua | (ub << 16);
}
__device__ __forceinline__ unsigned pack_f16(float a, float b){
  return __builtin_bit_cast(unsigned, __builtin_amdgcn_cvt_pkrtz(a, b));
}
#define BF_LO(u) __uint_as_float((u) << 16)
#define BF_HI(u) __uint_as_float((u) & 0xffff0000u)

// ---- CSR build: histogram, scan, scatter ----
__global__ __launch_bounds__(256) void k_count(const int* __restrict__ idx_i,
                                               int* __restrict__ cnt, int P)
{
  int p = blockIdx.x * blockDim.x + threadIdx.x;
  if (p < P) atomicAdd(&cnt[idx_i[p]], 1);
}

__global__ __launch_bounds__(1024) void k_scan(const int* __restrict__ cnt,
                                               int* __restrict__ start,
                                               int* __restrict__ cursor, int N)
{
  __shared__ int part[1024];
  int t = threadIdx.x;
  int chunk = (N + 1023) / 1024;
  int lo = t * chunk, hi = lo + chunk; if (hi > N) hi = N;
  int s = 0;
  for (int i = lo; i < hi; ++i) s += cnt[i];
  part[t] = s;
  __syncthreads();
  for (int off = 1; off < 1024; off <<= 1){
    int v = 0;
    if (t >= off) v = part[t - off];
    __syncthreads();
    if (t >= off) part[t] += v;
    __syncthreads();
  }
  int run = (t == 0) ? 0 : part[t-1];
  for (int i = lo; i < hi; ++i){ start[i] = run; cursor[i] = run; run += cnt[i]; }
  if (t == 1023) start[N] = run;
}

__global__ __launch_bounds__(256) void k_scatter(const int* __restrict__ idx_i,
                                                 int* __restrict__ cursor,
                                                 int* __restrict__ elist, int P)
{
  int p = blockIdx.x * blockDim.x + threadIdx.x;
  if (p < P){
    int pos = atomicAdd(&cursor[idx_i[p]], 1);
    elist[pos] = p;
  }
}

// ---- edge records in CSR order, 64B each:
// [0..3]=dir(3)+fcut (f32); [4..13]=phi*fcut packed f16 pairs; [14..15]=pad ----
__global__ __launch_bounds__(256) void k_edgeprep(const float* __restrict__ Rij,
                                                  const int* __restrict__ elist,
                                                  const int* __restrict__ idx_j,
                                                  float* __restrict__ eP,
                                                  int* __restrict__ eJ, int P)
{
  int e = blockIdx.x * blockDim.x + threadIdx.x;
  if (e >= P) return;
  int p = elist[e];
  eJ[e] = idx_j[p];
  float rx = Rij[3*p+0], ry = Rij[3*p+1], rz = Rij[3*p+2];
  float d = sqrtf(rx*rx + ry*ry + rz*rz);
  float inv = 1.0f / d;
  float fc = (d < CUT) ? 0.5f * (__cosf(PI_F * d / CUT) + 1.0f) : 0.0f;
  float* pr = eP + (size_t)e * 16;
  pr[0] = rx*inv; pr[1] = ry*inv; pr[2] = rz*inv; pr[3] = fc;
  const float width = CUT / (float)(NRBF - 1);
  float ph[NRBF];
#pragma unroll
  for (int r = 0; r < NRBF; ++r){
    float t = (d - width * (float)r) / width;
    ph[r] = __expf(-0.5f * t * t) * fc;
  }
  unsigned* pu = (unsigned*)(pr + 4);
#pragma unroll
  for (int r = 0; r < 10; ++r) pu[r] = pack_f16(ph[2*r], ph[2*r+1]);
  pr[14] = 0.f; pr[15] = 0.f;
}

// ---- transpose rec_W2 -> f16 rW2S in [l][c][kq][f][8] layout; rb2 -> rb2T ----
__global__ __launch_bounds__(256) void k_transpose_w(const float* __restrict__ rW2,
                                                     const float* __restrict__ rb2,
                                                     unsigned short* __restrict__ rW2S,
                                                     float* __restrict__ rb2T)
{
  int t = blockIdx.x * blockDim.x + threadIdx.x;
  if (t < 2*64*64*32){
    int km = t & 7;
    int f  = (t >> 3) & 63;
    int kq = (t >> 9) & 3;
    int c  = (t >> 11) & 63;
    int l  = t >> 17;
    int k  = kq*8 + km;
    float v = rW2[((size_t)(l*32 + k))*4096 + f*64 + c];
    _Float16 hv = (_Float16)v;
    unsigned short us;
    __builtin_memcpy(&us, &hv, 2);
    rW2S[t] = us;
  }
  if (t < 2*64*64){
    int f = t & 63, c = (t >> 6) & 63, l = t >> 12;
    rb2T[t] = rb2[(size_t)l*4096 + f*64 + c];
  }
}

// ---- K_init: q = embed[Z] ----
__global__ __launch_bounds__(256) void k_init_q(const int* __restrict__ Z,
                                                const float* __restrict__ embed,
                                                float* __restrict__ q, int Ntot)
{
  int t = blockIdx.x * blockDim.x + threadIdx.x;
  if (t >= Ntot * FD) return;
  int n = t >> 6, f = t & 63;
  q[t] = embed[Z[n]*FD + f];
}

// ---- K1: per-atom pre. 16 atoms/block, weights LDS-staged. ----
__global__ __launch_bounds__(256) void k_atom_pre(
    const float* __restrict__ q, const float* __restrict__ mu,
    const float* __restrict__ cW1, const float* __restrict__ cb1,
    const float* __restrict__ cW2, const float* __restrict__ cb2,
    const float* __restrict__ pW1, const float* __restrict__ pb1,
    const float* __restrict__ pW2, const float* __restrict__ pb2,
    unsigned* __restrict__ XCVh, float* __restrict__ CVf, int Ntot)
{
  __shared__ float wbuf[12288];     // 48 KB
  __shared__ float qs[16][64];      // 4 KB
  __shared__ float sbuf[16][128];   // 8 KB
  __shared__ float h1s[16][64];     // 4 KB
  __shared__ float hcs[16][32];     // 2 KB
  int t = threadIdx.x;
  int w = t >> 6, f = t & 63;
  int base = blockIdx.x * 16;
  const int aw = w * 4;
  float4* wt4 = (float4*)wbuf;

  float m0a[4], m1a[4], m2a[4], m0b[4], m1b[4], m2b[4];
#pragma unroll
  for (int s = 0; s < 4; ++s){
    int a = aw + s;
    int n = base + a; if (n >= Ntot) n = Ntot - 1;
    qs[a][f] = q[(size_t)n*64 + f];
    const float* mun = mu + (size_t)n * 384;
    m0a[s] = mun[0*128 + f];      m1a[s] = mun[1*128 + f];      m2a[s] = mun[2*128 + f];
    m0b[s] = mun[0*128 + 64 + f]; m1b[s] = mun[1*128 + 64 + f]; m2b[s] = mun[2*128 + 64 + f];
    sbuf[a][f]      = sqrtf(m0a[s]*m0a[s] + m1a[s]*m1a[s] + m2a[s]*m2a[s] + EPSV);
    sbuf[a][64 + f] = sqrtf(m0b[s]*m0b[s] + m1b[s]*m1b[s] + m2b[s]*m2b[s] + EPSV);
  }
#pragma unroll
  for (int i = 0; i < 4; ++i) wt4[t + i*256] = ((const float4*)cW1)[t + i*256];
  __syncthreads();

  float hacc[4];
#pragma unroll
  for (int s = 0; s < 4; ++s) hacc[s] = cb1[f];
  for (int k = 0; k < 64; ++k){
    float wv = wbuf[k*64 + f];
#pragma unroll
    for (int s = 0; s < 4; ++s) hacc[s] = fmaf(qs[aw + s][k], wv, hacc[s]);
  }
#pragma unroll
  for (int s = 0; s < 4; ++s) h1s[aw + s][f] = silu_f(hacc[s]);

  __syncthreads();
#pragma unroll
  for (int i = 0; i < 12; ++i) wt4[t + i*256] = ((const float4*)cW2)[t + i*256];
  __syncthreads();

  float x0[4], x1[4], x2[4];
#pragma unroll
  for (int s = 0; s < 4; ++s){ x0[s] = cb2[f]; x1[s] = cb2[64+f]; x2[s] = cb2[128+f]; }
  for (int k = 0; k < 64; ++k){
    float u0 = wbuf[k*192 + f];
    float u1 = wbuf[k*192 + 64 + f];
    float u2 = wbuf[k*192 + 128 + f];
#pragma unroll
    for (int s = 0; s < 4; ++s){
      float h = h1s[aw + s][k];
      x0[s] = fmaf(h, u0, x0[s]); x1[s] = fmaf(h, u1, x1[s]); x2[s] = fmaf(h, u2, x2[s]);
    }
  }
#pragma unroll
  for (int s = 0; s < 4; ++s){
    int n = base + aw + s;
    if (n < Ntot) XCVh[(size_t)n*192 + f] = pack_bf16(x0[s], x1[s]);
  }

  __syncthreads();
#pragma unroll
  for (int i = 0; i < 4; ++i) wt4[t + i*256] = ((const float4*)pW1)[t + i*256];
#pragma unroll
  for (int i = 0; i < 2; ++i) wt4[1024 + t + i*256] = ((const float4*)pW2)[t + i*256];
  __syncthreads();

  int ki = f & 31;
#pragma unroll
  for (int p = 0; p < 2; ++p){
    int a_h = aw + p*2 + (f >> 5);
    float ah = pb1[ki];
#pragma unroll 4
    for (int c = 0; c < 128; ++c) ah = fmaf(sbuf[a_h][c], wbuf[c*32 + ki], ah);
    hcs[a_h][ki] = fmaxf(ah, 0.0f);
  }

  float logit[4];
#pragma unroll
  for (int s = 0; s < 4; ++s) logit[s] = pb2[f];
  for (int k = 0; k < 32; ++k){
    float wv = wbuf[4096 + k*64 + f];
#pragma unroll
    for (int s = 0; s < 4; ++s) logit[s] = fmaf(hcs[aw + s][k], wv, logit[s]);
  }
#pragma unroll
  for (int s = 0; s < 4; ++s){
    float mx = wredmax(logit[s]);
    float e  = __expf(logit[s] - mx);
    float se = wredsum(e);
    float wt = e / se;
    float v0 = wredsum(m0a[s] + m0b[s]);
    float v1 = wredsum(m1a[s] + m1b[s]);
    float v2 = wredsum(m2a[s] + m2b[s]);
    int n = base + aw + s;
    if (n < Ntot){
      float cv0 = v0 * wt, cv1 = v1 * wt, cv2 = v2 * wt;
      XCVh[(size_t)n*192 + 64 + f]  = pack_bf16(x2[s], cv0);
      XCVh[(size_t)n*192 + 128 + f] = pack_bf16(cv1, cv2);
      float* cvn = CVf + (size_t)n*192;
      cvn[f] = cv0; cvn[64+f] = cv1; cvn[128+f] = cv2;
    }
  }
}

// ---- K2: gather, unroll-4 edge pipeline (latency hiding), fdot2 MLP, bf16 XCV. ----
__global__ __launch_bounds__(256) void k_gather(
    const float* __restrict__ eP, const int* __restrict__ eJ,
    const int* __restrict__ start,
    const float* __restrict__ fW, const float* __restrict__ fb,
    const unsigned* __restrict__ XCVh,
    float* __restrict__ dq, float* __restrict__ dmu, int l, int Ntot)
{
  int w = threadIdx.x >> 6;
  int f = threadIdx.x & 63;
  int i = blockIdx.x * 4 + w;
  if (i >= Ntot) return;
  const int col = l * 192;

  unsigned fwp0[10], fwp1[10], fwp2[10];
#pragma unroll
  for (int r = 0; r < 10; ++r){
    const float* fa = fW + (2*r)*384 + col;
    const float* fbp = fW + (2*r+1)*384 + col;
    fwp0[r] = pack_f16(fa[f],       fbp[f]);
    fwp1[r] = pack_f16(fa[64 + f],  fbp[64 + f]);
    fwp2[r] = pack_f16(fa[128 + f], fbp[128 + f]);
  }
  float fb0 = fb[col + f], fb1 = fb[col + 64 + f], fb2 = fb[col + 128 + f];

  float dqa = 0.f, dm0 = 0.f, dm1 = 0.f, dm2 = 0.f;
  int e0 = start[i], e1 = start[i+1];
  int e = e0;
  for (; e + 4 <= e1; e += 4){
    int jj[4];
    float4 d4[4];
    uint4  p0[4], p1[4], p2[4];
    unsigned xv0[4], xv1[4], xv2[4];
#pragma unroll
    for (int u = 0; u < 4; ++u) jj[u] = eJ[e + u];
#pragma unroll
    for (int u = 0; u < 4; ++u){
      const float4* pr = (const float4*)(eP + (size_t)(e + u) * 16);
      const uint4*  pui = (const uint4*)pr;
      d4[u] = pr[0]; p0[u] = pui[1]; p1[u] = pui[2]; p2[u] = pui[3];
    }
#pragma unroll
    for (int u = 0; u < 4; ++u){
      const unsigned* xj = XCVh + (size_t)jj[u] * 192;
      xv0[u] = xj[f]; xv1[u] = xj[64 + f]; xv2[u] = xj[128 + f];
    }
#pragma unroll
    for (int u = 0; u < 4; ++u){
      unsigned ph[10] = {p0[u].x,p0[u].y,p0[u].z,p0[u].w,
                         p1[u].x,p1[u].y,p1[u].z,p1[u].w,
                         p2[u].x,p2[u].y};
      float fc = d4[u].w;
      float w0 = fb0 * fc, w1 = fb1 * fc, w2 = fb2 * fc;
#pragma unroll
      for (int r = 0; r < 10; ++r){
        w0 = __builtin_amdgcn_fdot2(as_h2(ph[r]), as_h2(fwp0[r]), w0, false);
        w1 = __builtin_amdgcn_fdot2(as_h2(ph[r]), as_h2(fwp1[r]), w1, false);
        w2 = __builtin_amdgcn_fdot2(as_h2(ph[r]), as_h2(fwp2[r]), w2, false);
      }
      dqa = fmaf(BF_LO(xv0[u]), w0, dqa);
      float dmR = BF_HI(xv0[u]) * w1, dmm = BF_LO(xv1[u]) * w2;
      dm0 = fmaf(dmR, d4[u].x, fmaf(dmm, BF_HI(xv1[u]), dm0));
      dm1 = fmaf(dmR, d4[u].y, fmaf(dmm, BF_LO(xv2[u]), dm1));
      dm2 = fmaf(dmR, d4[u].z, fmaf(dmm, BF_HI(xv2[u]), dm2));
    }
  }
  for (; e < e1; ++e){
    int j = eJ[e];
    const float4* pr = (const float4*)(eP + (size_t)e * 16);
    const uint4*  pu = (const uint4*)pr;
    float4 A0 = pr[0];
    uint4  Ap0 = pu[1], Ap1 = pu[2], Ap2 = pu[3];
    const unsigned* xj = XCVh + (size_t)j * 192;
    unsigned u0=xj[f], u1=xj[64+f], u2=xj[128+f];
    unsigned ph[10] = {Ap0.x,Ap0.y,Ap0.z,Ap0.w, Ap1.x,Ap1.y,Ap1.z,Ap1.w, Ap2.x,Ap2.y};
    float w0 = fb0 * A0.w, w1 = fb1 * A0.w, w2 = fb2 * A0.w;
#pragma unroll
    for (int r = 0; r < 10; ++r){
      w0 = __builtin_amdgcn_fdot2(as_h2(ph[r]), as_h2(fwp0[r]), w0, false);
      w1 = __builtin_amdgcn_fdot2(as_h2(ph[r]), as_h2(fwp1[r]), w1, false);
      w2 = __builtin_amdgcn_fdot2(as_h2(ph[r]), as_h2(fwp2[r]), w2, false);
    }
    dqa = fmaf(BF_LO(u0), w0, dqa);
    float dmR = BF_HI(u0) * w1, dmm = BF_LO(u1) * w2;
    dm0 = fmaf(dmR, A0.x, fmaf(dmm, BF_HI(u1), dm0));
    dm1 = fmaf(dmR, A0.y, fmaf(dmm, BF_LO(u2), dm1));
    dm2 = fmaf(dmR, A0.z, fmaf(dmm, BF_HI(u2), dm2));
  }
  dq[(size_t)i*64 + f] = dqa;
  float* dmn = dmu + (size_t)i*192;
  dmn[f] = dm0; dmn[64 + f] = dm1; dmn[128 + f] = dm2;
}

// ---- K3a: tv with f16 [c][kq][f][8] tiles (conflict-free) + fdot2. ----
__global__ __launch_bounds__(512) void k_tv(
    const float* __restrict__ dmuA, const float* __restrict__ CVf,
    const float* __restrict__ rW1, const float* __restrict__ rb1,
    const unsigned short* __restrict__ rW2S, const float* __restrict__ rb2Tl,
    float* __restrict__ MUI, float* __restrict__ TV, int Ntot)
{
  __shared__ float mus[16][3][64];  // 12 KB
  __shared__ float svs[16][64];     // 4 KB
  __shared__ float4 wt4[2048];      // 32 KB
  __shared__ float rbt[8][64];      // 2 KB
  int t = threadIdx.x;
  int w = t >> 6, f = t & 63;
  int base = blockIdx.x * 16;

#pragma unroll
  for (int s = 0; s < 2; ++s){
    int a = w*2 + s;
    int n = base + a; bool ok = (n < Ntot); if (!ok) n = Ntot - 1;
    const float* dmn = dmuA + (size_t)n*192;
    const float* cvn = CVf  + (size_t)n*192;
    float m0 = dmn[f]       + cvn[f];
    float m1 = dmn[64 + f]  + cvn[64 + f];
    float m2 = dmn[128 + f] + cvn[128 + f];
    mus[a][0][f] = m0; mus[a][1][f] = m1; mus[a][2][f] = m2;
    svs[a][f] = sqrtf(m0*m0 + m1*m1 + m2*m2 + EPSV);
    if (ok){
      float* mo = MUI + (size_t)n*192;
      mo[f] = m0; mo[64+f] = m1; mo[128+f] = m2;
    }
  }
  __syncthreads();

  int ki = f & 31;
  int a_h = w*2 + (f >> 5);
  float ah = rb1[ki];
#pragma unroll
  for (int c = 0; c < 64; ++c) ah = fmaf(svs[a_h][c], rW1[c*32 + ki], ah);
  ah = fmaxf(ah, 0.0f);
  unsigned hpk0[16], hpk1[16];
#pragma unroll
  for (int k = 0; k < 16; ++k){
    float a0 = __shfl(ah, 2*k, 64),      b0 = __shfl(ah, 2*k + 1, 64);
    float a1 = __shfl(ah, 32 + 2*k, 64), b1 = __shfl(ah, 32 + 2*k + 1, 64);
    hpk0[k] = pack_f16(a0, b0);
    hpk1[k] = pack_f16(a1, b1);
  }

  const int a0i = w*2, a1i = a0i + 1;
  float mf00 = mus[a0i][0][f], mf01 = mus[a0i][1][f], mf02 = mus[a0i][2][f];
  float mf10 = mus[a1i][0][f], mf11 = mus[a1i][1][f], mf12 = mus[a1i][2][f];
  float tv00=0,tv01=0,tv02=0, tv10=0,tv11=0,tv12=0;
  const uint4* wtu = reinterpret_cast<const uint4*>(wt4);

  for (int ct = 0; ct < 8; ++ct){
    __syncthreads();
    const float4* src = (const float4*)rW2S + (size_t)ct*2048;
#pragma unroll
    for (int i = 0; i < 4; ++i) wt4[t + i*512] = src[t + i*512];
    if (t < 128) ((float4*)rbt)[t] = ((const float4*)(rb2Tl + ct*512))[t];
    __syncthreads();

#pragma unroll
    for (int cc = 0; cc < 8; ++cc){
      int c = ct*8 + cc;
      float u00 = mus[a0i][0][c], u01 = mus[a0i][1][c], u02 = mus[a0i][2][c];
      float u10 = mus[a1i][0][c], u11 = mus[a1i][1][c], u12 = mus[a1i][2][c];
      float g0 = u00*mf00 + u01*mf01 + u02*mf02;
      float g1 = u10*mf10 + u11*mf11 + u12*mf12;
      float acc0 = rbt[cc][f];
      float acc1 = acc0;
#pragma unroll
      for (int kq = 0; kq < 4; ++kq){
        uint4 u = wtu[(cc*4 + kq)*64 + f];
        int k0 = kq*4;
        acc0 = __builtin_amdgcn_fdot2(as_h2(u.x), as_h2(hpk0[k0+0]), acc0, false);
        acc0 = __builtin_amdgcn_fdot2(as_h2(u.y), as_h2(hpk0[k0+1]), acc0, false);
        acc0 = __builtin_amdgcn_fdot2(as_h2(u.z), as_h2(hpk0[k0+2]), acc0, false);
        acc0 = __builtin_amdgcn_fdot2(as_h2(u.w), as_h2(hpk0[k0+3]), acc0, false);
        acc1 = __builtin_amdgcn_fdot2(as_h2(u.x), as_h2(hpk1[k0+0]), acc1, false);
        acc1 = __builtin_amdgcn_fdot2(as_h2(u.y), as_h2(hpk1[k0+1]), acc1, false);
        acc1 = __builtin_amdgcn_fdot2(as_h2(u.z), as_h2(hpk1[k0+2]), acc1, false);
        acc1 = __builtin_amdgcn_fdot2(as_h2(u.w), as_h2(hpk1[k0+3]), acc1, false);
      }
      float mm0 = acc0 * g0, mm1 = acc1 * g1;
      tv00 = fmaf(u00, mm0, tv00); tv01 = fmaf(u01, mm0, tv01); tv02 = fmaf(u02, mm0, tv02);
      tv10 = fmaf(u10, mm1, tv10); tv11 = fmaf(u11, mm1, tv11); tv12 = fmaf(u12, mm1, tv12);
    }
  }

  int n0 = base + a0i, n1 = base + a1i;
  if (n0 < Ntot){
    float* tvp = TV + (size_t)n0*192;
    tvp[f] = tv00; tvp[64+f] = tv01; tvp[128+f] = tv02;
  }
  if (n1 < Ntot){
    float* tvp = TV + (size_t)n1*192;
    tvp[f] = tv10; tvp[64+f] = tv11; tvp[128+f] = tv12;
  }
}

// ---- K3b: mixing tail. 16 atoms/block (4 per wave), weights LDS-staged. ----
__global__ __launch_bounds__(256) void k_mix2(
    float* __restrict__ q, float* __restrict__ mu,
    const float* __restrict__ dq, const float* __restrict__ MUI, const float* __restrict__ TV,
    const float* __restrict__ mW1, const float* __restrict__ mb1,
    const float* __restrict__ mW2, const float* __restrict__ mb2,
    const float* __restrict__ Wm, int Ntot)
{
  __shared__ float wbuf[12288];     // 48 KB
  __shared__ float mua[16][3][64];  // 12 KB
  __shared__ float ava[16][128];    // 8 KB
  __shared__ float h2a[16][64];     // 4 KB
  int t = threadIdx.x;
  int w = t >> 6, f = t & 63;
  int base = blockIdx.x * 16;
  const int aw = w * 4;
  float4* wt4 = (float4*)wbuf;

  float qv[4], m0[4], m1[4], m2[4];
#pragma unroll
  for (int s = 0; s < 4; ++s){
    int a = aw + s;
    int n = base + a; if (n >= Ntot) n = Ntot - 1;
    qv[s] = q[(size_t)n*64 + f] + dq[(size_t)n*64 + f];
    const float* mi = MUI + (size_t)n*192;
    m0[s] = mi[f]; m1[s] = mi[64 + f]; m2[s] = mi[128 + f];
    mua[a][0][f] = m0[s]; mua[a][1][f] = m1[s]; mua[a][2][f] = m2[s];
  }

#pragma unroll
  for (int i = 0; i < 8; ++i) wt4[t + i*256] = ((const float4*)Wm)[t + i*256];
  __syncthreads();

  float V0[4]={0,0,0,0}, V1[4]={0,0,0,0}, V2[4]={0,0,0,0};
  float W0[4]={0,0,0,0}, W1[4]={0,0,0,0}, W2[4]={0,0,0,0};
  for (int k = 0; k < 64; ++k){
    float wv = wbuf[k*128 + f];
    float ww = wbuf[k*128 + 64 + f];
#pragma unroll
    for (int s = 0; s < 4; ++s){
      int a = aw + s;
      float b0 = mua[a][0][k], b1 = mua[a][1][k], b2 = mua[a][2][k];
      V0[s] = fmaf(b0, wv, V0[s]); V1[s] = fmaf(b1, wv, V1[s]); V2[s] = fmaf(b2, wv, V2[s]);
      W0[s] = fmaf(b0, ww, W0[s]); W1[s] = fmaf(b1, ww, W1[s]); W2[s] = fmaf(b2, ww, W2[s]);
    }
  }
  float dot[4];
#pragma unroll
  for (int s = 0; s < 4; ++s){
    int a = aw + s;
    ava[a][f] = qv[s];
    ava[a][64 + f] = sqrtf(V0[s]*V0[s] + V1[s]*V1[s] + V2[s]*V2[s] + EPSV);
    dot[s] = V0[s]*W0[s] + V1[s]*W1[s] + V2[s]*W2[s];
  }

  __syncthreads();
#pragma unroll
  for (int i = 0; i < 8; ++i) wt4[t + i*256] = ((const float4*)mW1)[t + i*256];
  __syncthreads();

  float acc[4];
#pragma unroll
  for (int s = 0; s < 4; ++s) acc[s] = mb1[f];
  for (int k = 0; k < 128; ++k){
    float wv = wbuf[k*64 + f];
#pragma unroll
    for (int s = 0; s < 4; ++s) acc[s] = fmaf(ava[aw + s][k], wv, acc[s]);
  }
#pragma unroll
  for (int s = 0; s < 4; ++s) h2a[aw + s][f] = silu_f(acc[s]);

  __syncthreads();
#pragma unroll
  for (int i = 0; i < 12; ++i) wt4[t + i*256] = ((const float4*)mW2)[t + i*256];
  __syncthreads();

  float y0[4], y1[4], y2[4];
#pragma unroll
  for (int s = 0; s < 4; ++s){ y0[s] = mb2[f]; y1[s] = mb2[64+f]; y2[s] = mb2[128+f]; }
  for (int k = 0; k < 64; ++k){
    float u0 = wbuf[k*192 + f];
    float u1 = wbuf[k*192 + 64 + f];
    float u2 = wbuf[k*192 + 128 + f];
#pragma unroll
    for (int s = 0; s < 4; ++s){
      float h = h2a[aw + s][k];
      y0[s] = fmaf(h, u0, y0[s]); y1[s] = fmaf(h, u1, y1[s]); y2[s] = fmaf(h, u2, y2[s]);
    }
  }

#pragma unroll
  for (int s = 0; s < 4; ++s){
    int n = base + aw + s;
    if (n < Ntot){
      q[(size_t)n*64 + f] = qv[s] + y0[s] + y2[s]*dot[s];
      const float* tvp = TV + (size_t)n*192;
      float* mun = mu + (size_t)n*384;
      mun[0*128 + f] = fmaf(y1[s], W0[s], m0[s]); mun[0*128 + 64 + f] = tvp[f];
      mun[1*128 + f] = fmaf(y1[s], W1[s], m1[s]); mun[1*128 + 64 + f] = tvp[64+f];
      mun[2*128 + f] = fmaf(y1[s], W2[s], m2[s]); mun[2*128 + 64 + f] = tvp[128+f];
    }
  }
}

extern "C" void kernel_launch(void* const* d_in, const int* in_sizes, int n_in,
                              void* d_out, int out_size, void* d_ws, size_t ws_size,
                              hipStream_t stream)
{
  const int*   Z      = (const int*)  d_in[0];
  const float* Rij    = (const float*)d_in[1];
  const int*   idx_i  = (const int*)  d_in[2];
  const int*   idx_j  = (const int*)  d_in[3];
  const float* embed  = (const float*)d_in[5];
  const float* fW     = (const float*)d_in[6];
  const float* fb     = (const float*)d_in[7];
  const float* ctxW1  = (const float*)d_in[8];
  const float* ctxb1  = (const float*)d_in[9];
  const float* ctxW2  = (const float*)d_in[10];
  const float* ctxb2  = (const float*)d_in[11];
  const float* compW1 = (const float*)d_in[12];
  const float* compb1 = (const float*)d_in[13];
  const float* compW2 = (const float*)d_in[14];
  const float* compb2 = (const float*)d_in[15];
  const float* recW1  = (const float*)d_in[16];
  const float* recb1  = (const float*)d_in[17];
  const float* recW2  = (const float*)d_in[18];
  const float* recb2  = (const float*)d_in[19];
  const float* mixW1  = (const float*)d_in[20];
  const float* mixb1  = (const float*)d_in[21];
  const float* mixW2  = (const float*)d_in[22];
  const float* mixb2  = (const float*)d_in[23];
  const float* muMixW = (const float*)d_in[24];

  const int N = in_sizes[0];
  const int P = in_sizes[1] / 3;

  float* ws    = (float*)d_ws;
  float* eP    = ws;                         // P*16 (64B records)
  float* q     = eP    + (size_t)P*16;       // N*64
  float* mu    = q     + (size_t)N*64;       // N*384
  float* XCVhf = mu    + (size_t)N*384;      // N*192 (uints)
  float* CVf   = XCVhf + (size_t)N*192;      // N*192
  float* dq    = CVf   + (size_t)N*192;      // N*64
  float* dmu   = dq    + (size_t)N*64;       // N*192
  float* rW2Sf = dmu   + (size_t)N*192;      // f16 512KB = 131072 floats
  float* rb2T  = rW2Sf + (size_t)131072;     // 8192
  float* TV    = rb2T  + (size_t)8192;       // N*192
  float* MUI   = TV    + (size_t)N*192;      // N*192
  int*   cnt    = (int*)(MUI + (size_t)N*192); // N
  int*   startA = cnt    + N;                  // N+1
  int*   cursor = startA + (N + 1);            // N
  int*   elist  = cursor + N;                  // P
  int*   eJ     = elist  + P;                  // P
  unsigned*       XCVh = (unsigned*)XCVhf;
  unsigned short* rW2S = (unsigned short*)rW2Sf;

  hipMemsetAsync(mu, 0, (size_t)N*384*sizeof(float), stream);
  hipMemsetAsync(cnt, 0, (size_t)N*sizeof(int), stream);
  k_init_q<<<(N*FD + 255)/256, 256, 0, stream>>>(Z, embed, q, N);
  k_transpose_w<<<(2*64*64*32 + 255)/256, 256, 0, stream>>>(recW2, recb2, rW2S, rb2T);

  // CSR build + CSR-ordered edge records (idx fixed across layers)
  k_count<<<(P + 255)/256, 256, 0, stream>>>(idx_i, cnt, P);
  k_scan<<<1, 1024, 0, stream>>>(cnt, startA, cursor, N);
  k_scatter<<<(P + 255)/256, 256, 0, stream>>>(idx_i, cursor, elist, P);
  k_edgeprep<<<(P + 255)/256, 256, 0, stream>>>(Rij, elist, idx_j, eP, eJ, P);

  const int ablk4  = (N + 3) / 4;
  const int ablk16 = (N + 15) / 16;
  for (int l = 0; l < 2; ++l){
    k_atom_pre<<<ablk16, 256, 0, stream>>>(q, mu,
        ctxW1 + (size_t)l*64*64,  ctxb1 + (size_t)l*64,
        ctxW2 + (size_t)l*64*192, ctxb2 + (size_t)l*192,
        compW1 + (size_t)l*128*32, compb1 + (size_t)l*32,
        compW2 + (size_t)l*32*64,  compb2 + (size_t)l*64,
        XCVh, CVf, N);
    k_gather<<<ablk4, 256, 0, stream>>>(eP, eJ, startA, fW, fb, XCVh,
        dq, dmu, l, N);
    k_tv<<<ablk16, 512, 0, stream>>>(dmu, CVf,
        recW1 + (size_t)l*64*32, recb1 + (size_t)l*32,
        rW2S + (size_t)l*131072, rb2T + (size_t)l*4096,
        MUI, TV, N);
    k_mix2<<<ablk16, 256, 0, stream>>>(q, mu, dq, MUI, TV,
        mixW1 + (size_t)l*128*64, mixb1 + (size_t)l*64,
        mixW2 + (size_t)l*64*192, mixb2 + (size_t)l*192,
        muMixW + (size_t)l*64*128, N);
  }

  hipMemcpyAsync(d_out, q, (size_t)N*64*sizeof(float), hipMemcpyDeviceToDevice, stream);
  hipMemcpyAsync((float*)d_out + (size_t)N*64, mu, (size_t)N*384*sizeof(float),
                 hipMemcpyDeviceToDevice, stream);
}